// Round 2
// baseline (457.647 us; speedup 1.0000x reference)
//
#include <hip/hip_runtime.h>
#include <hip/hip_bf16.h>

// ---------------------------------------------------------------------------
// Compile-time generation of real-basis Wigner-3j tables (exact translation of
// the Python reference: _su2_cg, _q_real_to_complex, _w3j, normalized).
// Each key evaluated as its own constexpr variable to stay under clang's
// constexpr step limit.
// ---------------------------------------------------------------------------
namespace w3j_gen {

struct FactT { double f[16]; };
constexpr FactT make_fact() {
    FactT t{}; t.f[0] = 1.0;
    for (int i = 1; i < 16; i++) t.f[i] = t.f[i-1] * (double)i;
    return t;
}
constexpr FactT FT = make_fact();

constexpr double csqrt(double x) {
    if (x <= 0.0) return 0.0;
    double g = x < 1.0 ? 1.0 : x;
    for (int i = 0; i < 80; i++) g = 0.5 * (g + x / g);
    return g;
}

constexpr int imax3(int a, int b, int c) { int m = a; if (b > m) m = b; if (c > m) m = c; return m; }
constexpr int imin3(int a, int b, int c) { int m = a; if (b < m) m = b; if (c < m) m = c; return m; }

constexpr double su2_cg(int j1, int m1, int j2, int m2, int j3, int m3) {
    if (m3 != m1 + m2) return 0.0;
    double pref = csqrt((double)(2*j3+1) * FT.f[j3+j1-j2] * FT.f[j3-j1+j2] * FT.f[j1+j2-j3] / FT.f[j1+j2+j3+1]);
    pref *= csqrt(FT.f[j3+m3] * FT.f[j3-m3] * FT.f[j1-m1] * FT.f[j1+m1] * FT.f[j2-m2] * FT.f[j2+m2]);
    int kmin = imax3(0, j2-j3-m1, j1-j3+m2);
    int kmax = imin3(j1+j2-j3, j1-m1, j2+m2);
    double s = 0.0;
    for (int k = kmin; k <= kmax; k++) {
        double d = FT.f[k] * FT.f[j1+j2-j3-k] * FT.f[j1-m1-k] * FT.f[j2+m2-k] * FT.f[j3-j2+m1+k] * FT.f[j3-j1-m2+k];
        s += ((k & 1) ? -1.0 : 1.0) / d;
    }
    return pref * s;
}

struct CD { double re, im; };
struct QT { CD q[7][7]; };

constexpr QT make_q(int l) {
    QT t{};
    const double is2 = csqrt(0.5);
    for (int m = -l; m < 0; m++) {
        t.q[l+m][l-m].re = is2;    // col l+|m|: 1/sqrt2
        t.q[l+m][l+m].im = -is2;   // col l-|m|: -i/sqrt2
    }
    t.q[l][l].re = 1.0;
    for (int m = 1; m <= l; m++) {
        double s = (m & 1) ? -1.0 : 1.0;
        t.q[l+m][l+m].re = s * is2;
        t.q[l+m][l-m].im = s * is2;
    }
    // multiply by (-i)^l
    CD ph = {1.0, 0.0};
    if (l % 4 == 1) ph = {0.0, -1.0};
    else if (l % 4 == 2) ph = {-1.0, 0.0};
    else if (l % 4 == 3) ph = {0.0, 1.0};
    for (int i = 0; i < 7; i++)
        for (int j = 0; j < 7; j++) {
            CD a = t.q[i][j];
            t.q[i][j] = { ph.re*a.re - ph.im*a.im, ph.re*a.im + ph.im*a.re };
        }
    return t;
}

struct Tab { float v[245]; };

// Cr[j,l,n] = Re( sum_{i,k,m} Q1[i,j] Q2[k,l] conj(Q3[n,m]) C[i,k,m] ), normalized.
constexpr Tab make_w3j(int l1, int l2, int l3) {
    const int n1 = 2*l1+1, n2 = 2*l2+1, n3 = 2*l3+1;
    double C[7][7][7] = {};
    for (int m1 = -l1; m1 <= l1; m1++)
        for (int m2 = -l2; m2 <= l2; m2++) {
            int m3 = m1 + m2;
            if (m3 >= -l3 && m3 <= l3)
                C[l1+m1][l2+m2][l3+m3] = su2_cg(l1, m1, l2, m2, l3, m3);
        }
    QT Q1 = make_q(l1), Q2 = make_q(l2), Q3 = make_q(l3);
    CD T1[7][7][7] = {};   // [j][k][m] = sum_i Q1[i][j] * C[i][k][m]
    for (int j = 0; j < n1; j++)
        for (int k = 0; k < n2; k++)
            for (int m = 0; m < n3; m++) {
                double sr = 0, si = 0;
                for (int i = 0; i < n1; i++) {
                    double cv = C[i][k][m];
                    sr += Q1.q[i][j].re * cv;
                    si += Q1.q[i][j].im * cv;
                }
                T1[j][k][m] = {sr, si};
            }
    CD T2[7][7][7] = {};   // [j][l][m] = sum_k Q2[k][l] * T1[j][k][m]
    for (int j = 0; j < n1; j++)
        for (int l = 0; l < n2; l++)
            for (int m = 0; m < n3; m++) {
                double sr = 0, si = 0;
                for (int k = 0; k < n2; k++) {
                    CD a = Q2.q[k][l], b = T1[j][k][m];
                    sr += a.re*b.re - a.im*b.im;
                    si += a.re*b.im + a.im*b.re;
                }
                T2[j][l][m] = {sr, si};
            }
    double Cr[7][7][7] = {};
    double nrm2 = 0.0;
    for (int j = 0; j < n1; j++)
        for (int l = 0; l < n2; l++)
            for (int n = 0; n < n3; n++) {
                double s = 0;
                for (int m = 0; m < n3; m++) {
                    CD a = Q3.q[n][m], b = T2[j][l][m];
                    s += a.re*b.re + a.im*b.im;   // Re(conj(a)*b)
                }
                Cr[j][l][n] = s;
                nrm2 += s * s;
            }
    double inv = 1.0 / csqrt(nrm2);
    Tab t{};
    for (int j = 0; j < n1; j++)
        for (int l = 0; l < n2; l++)
            for (int n = 0; n < n3; n++)
                t.v[(j*n2 + l)*n3 + n] = (float)(Cr[j][l][n] * inv);
    return t;
}

// 23 unique keys, lo-major, (la,lb)-lexicographic within lo (matches path order).
constexpr Tab T0  = make_w3j(0,0,0);
constexpr Tab T1_ = make_w3j(1,1,0);
constexpr Tab T2_ = make_w3j(2,2,0);
constexpr Tab T3_ = make_w3j(3,3,0);
constexpr Tab T4  = make_w3j(0,1,1);
constexpr Tab T5  = make_w3j(1,0,1);
constexpr Tab T6  = make_w3j(1,2,1);
constexpr Tab T7  = make_w3j(2,1,1);
constexpr Tab T8  = make_w3j(2,3,1);
constexpr Tab T9  = make_w3j(3,2,1);
constexpr Tab T10 = make_w3j(0,2,2);
constexpr Tab T11 = make_w3j(1,1,2);
constexpr Tab T12 = make_w3j(1,3,2);
constexpr Tab T13 = make_w3j(2,0,2);
constexpr Tab T14 = make_w3j(2,2,2);
constexpr Tab T15 = make_w3j(3,1,2);
constexpr Tab T16 = make_w3j(3,3,2);
constexpr Tab T17 = make_w3j(0,3,3);
constexpr Tab T18 = make_w3j(1,2,3);
constexpr Tab T19 = make_w3j(2,1,3);
constexpr Tab T20 = make_w3j(2,3,3);
constexpr Tab T21 = make_w3j(3,0,3);
constexpr Tab T22 = make_w3j(3,2,3);

// sizes: (2la+1)(2lb+1)(2lo+1).  Key 22 = (3,2,3) -> 7*5*7 = 245 (was the R1 bug).
struct AllW { float w[1875]; };
constexpr int KSZ[23] = {1,9,25,49, 9,9,45,45,105,105, 25,45,105,25,125,105,245, 49,105,105,245,49,245};
constexpr AllW make_all() {
    AllW a{};
    const Tab* ts[23] = {&T0,&T1_,&T2_,&T3_,&T4,&T5,&T6,&T7,&T8,&T9,&T10,&T11,
                         &T12,&T13,&T14,&T15,&T16,&T17,&T18,&T19,&T20,&T21,&T22};
    int off = 0;
    for (int t = 0; t < 23; t++) {
        for (int i = 0; i < KSZ[t]; i++) a.w[off+i] = ts[t]->v[i];
        off += KSZ[t];
    }
    return a;
}

} // namespace w3j_gen

__constant__ w3j_gen::AllW W3J_C = w3j_gen::make_all();
__constant__ int K_LA[23]   = {0,1,2,3, 0,1,1,2,2,3, 0,1,1,2,2,3,3, 0,1,2,2,3,3};
__constant__ int K_LB[23]   = {0,1,2,3, 1,0,2,1,3,2, 2,1,3,0,2,1,3, 3,2,1,3,0,2};
__constant__ int K_LO[23]   = {0,0,0,0, 1,1,1,1,1,1, 2,2,2,2,2,2,2, 3,3,3,3,3,3};
__constant__ int K_WOFF[23] = {0,1,10,35, 84,93,102,147,192,297, 402,427,472,577,602,727,832, 1077,1126,1231,1336,1581,1630};

#define N_EDGES   65536
#define ALL_BASE  75497472ull   // 65536 * 9 * 128

__device__ __forceinline__ float sigmoidf_(float v) { return 1.0f / (1.0f + __expf(-v)); }

__global__ __launch_bounds__(256)
void cg_interaction_kernel(
    const float* __restrict__ x, const float* __restrict__ y,
    const float* __restrict__ w_cg, const float* __restrict__ b_cg,
    const float* __restrict__ w_all, const float* __restrict__ b_all,
    float* __restrict__ out)
{
    __shared__ float sx[2][16];
    __shared__ float sy[2][16];
    __shared__ float sz[2][100];

    const int tid = threadIdx.x;
    const int e0 = blockIdx.x << 1;   // 2 edges per block

    if (tid < 32)       sx[tid >> 4][tid & 15] = x[(size_t)e0 * 16 + tid];
    else if (tid < 64) { int t = tid - 32; sy[t >> 4][t & 15] = y[(size_t)e0 * 16 + t]; }
    __syncthreads();

    const int half = tid >> 7;
    const int lane = tid & 127;

    // Phase 1: z[key][k] = sum_{i,j} x_i y_j W3J[key][i][j][k]  (99 slots/edge)
    if (lane < 99) {
        int key, k;
        if (lane < 4)       { key = lane; k = 0; }
        else if (lane < 22) { int t = lane - 4;  key = 4  + t / 3; k = t - (key - 4)  * 3; }
        else if (lane < 57) { int t = lane - 22; key = 10 + t / 5; k = t - (key - 10) * 5; }
        else                { int t = lane - 57; key = 17 + t / 7; k = t - (key - 17) * 7; }
        const int la = K_LA[key], lb = K_LB[key];
        const int n2 = 2 * lb + 1, n3 = 2 * K_LO[key] + 1;
        const float* W  = &W3J_C.w[K_WOFF[key] + k];
        const float* px = &sx[half][la * la];
        const float* py = &sy[half][lb * lb];
        float acc = 0.0f;
        for (int i = 0; i <= 2 * la; i++) {
            float xi = px[i];
            const float* Wi = W + i * n2 * n3;
            for (int j = 0; j < n2; j++) acc += xi * py[j] * Wi[j * n3];
        }
        sz[half][lane] = acc;
    }
    __syncthreads();

    // Phase 2: per-channel combination + gating + stores
    const float* z = sz[half];
    const size_t e = (size_t)(e0 + half);
    const int c = lane;
    const float z0 = z[0], z1 = z[1], z2 = z[2], z3 = z[3];

    // entry 0 (mul=128, lo=0): w_cg[0..511]
    float u0 = (z0*w_cg[c] + z1*w_cg[128+c] + z2*w_cg[256+c] + z3*w_cg[384+c]) * 0.5f + b_cg[c];
    float sc = u0 * sigmoidf_(u0);
    // entry 1 (mul=256, lo=0): w_cg[512..1535], gates
    float u1 = (z0*w_cg[512+c] + z1*w_cg[768+c] + z2*w_cg[1024+c] + z3*w_cg[1280+c]) * 0.5f + b_cg[128+c];
    float u2 = (z0*w_cg[640+c] + z1*w_cg[896+c] + z2*w_cg[1152+c] + z3*w_cg[1408+c]) * 0.5f + b_cg[256+c];
    float g1 = sigmoidf_(u1), g2 = sigmoidf_(u2);

    float wl1[6];
    #pragma unroll
    for (int p = 0; p < 6; p++) wl1[p] = w_cg[1536 + p * 128 + c];
    float wl2[7];
    #pragma unroll
    for (int p = 0; p < 7; p++) wl2[p] = w_cg[2304 + p * 128 + c];

    const float SQ12 = 0.70710678118654752f;   // sqrt(3/6)
    const float SQ57 = 0.84515425472851657f;   // sqrt(5/7)

    float* o = out + e * 1152;
    __builtin_nontemporal_store(sc, &o[c]);
    #pragma unroll
    for (int k = 0; k < 3; k++) {
        float s = 0.0f;
        #pragma unroll
        for (int p = 0; p < 6; p++) s += z[4 + 3*p + k] * wl1[p];
        __builtin_nontemporal_store(s * SQ12 * g1, &o[(1 + k) * 128 + c]);
    }
    #pragma unroll
    for (int k = 0; k < 5; k++) {
        float s = 0.0f;
        #pragma unroll
        for (int p = 0; p < 7; p++) s += z[22 + 5*p + k] * wl2[p];
        __builtin_nontemporal_store(s * SQ57 * g2, &o[(4 + k) * 128 + c]);
    }

    // cg_all: 16 values per edge, lanes 0..15
    if (c < 16) {
        const float SQ76 = 1.08012344973464f;  // sqrt(7/6)
        float v;
        if (c == 0) {
            float a = (z0*w_all[0] + z1*w_all[1] + z2*w_all[2] + z3*w_all[3]) * 0.5f + b_all[0];
            v = a * sigmoidf_(a);
        } else if (c < 4) {
            int k = c - 1;
            float s = 0.0f;
            #pragma unroll
            for (int p = 0; p < 6; p++) s += z[4 + 3*p + k] * w_all[16 + p];
            float g = (z0*w_all[4] + z1*w_all[7] + z2*w_all[10] + z3*w_all[13]) * 0.5f + b_all[1];
            v = s * SQ12 * sigmoidf_(g);
        } else if (c < 9) {
            int k = c - 4;
            float s = 0.0f;
            #pragma unroll
            for (int p = 0; p < 7; p++) s += z[22 + 5*p + k] * w_all[22 + p];
            float g = (z0*w_all[5] + z1*w_all[8] + z2*w_all[11] + z3*w_all[14]) * 0.5f + b_all[2];
            v = s * SQ57 * sigmoidf_(g);
        } else {
            int k = c - 9;
            float s = 0.0f;
            #pragma unroll
            for (int p = 0; p < 6; p++) s += z[57 + 7*p + k] * w_all[29 + p];
            float g = (z0*w_all[6] + z1*w_all[9] + z2*w_all[12] + z3*w_all[15]) * 0.5f + b_all[3];
            v = s * SQ76 * sigmoidf_(g);
        }
        out[ALL_BASE + e * 16 + c] = v;
    }
}

extern "C" void kernel_launch(void* const* d_in, const int* in_sizes, int n_in,
                              void* d_out, int out_size, void* d_ws, size_t ws_size,
                              hipStream_t stream) {
    const float* x     = (const float*)d_in[0];
    const float* y     = (const float*)d_in[1];
    const float* w_cg  = (const float*)d_in[2];
    const float* b_cg  = (const float*)d_in[3];
    const float* w_all = (const float*)d_in[4];
    const float* b_all = (const float*)d_in[5];
    float* out = (float*)d_out;

    dim3 grid(N_EDGES / 2), block(256);
    hipLaunchKernelGGL(cg_interaction_kernel, grid, block, 0, stream,
                       x, y, w_cg, b_cg, w_all, b_all, out);
}